// Round 16
// baseline (57.782 us; speedup 1.0000x reference)
//
#include <hip/hip_runtime.h>
#include <hip/hip_bf16.h>

// QuantumFeedForward, fully fused:
//   q[n,w] = prod_{v in M_w} cos(theta_v)*cos(x[n,v])   (analytic circuit collapse)
//   out    = relu(q@W1^T+b1) @ W2^T + b2
// 32x32x16 MFMA. H^T = mfma(W1aug-frag, qaug-frag) -> pk-relu -> v_cvt_pk_bf16_f32
// (RNE, verified R9-R14) -> v_permlane32_swap -> GEMM A-quads in registers.
// R16: R15's one-kt software pipeline (HGEN(kt+1) independent of GEMM(kt) ->
// scheduler interleaves all 10 mfma) with the VERIFIED RNE pack restored
// (R15's __float2bfloat16 pack was biased -> K-linear error accumulation, failed).
// 256-thread blocks (4 waves, 32x64 tiles), BM=128 x BN=64, grid 1024 = 4/CU.
// W2 B-frags LDS-staged in fragment order; one vmcnt(0)+s_barrier per kt.

typedef __attribute__((ext_vector_type(8))) short bf16x8;
typedef __attribute__((ext_vector_type(16))) float f32x16;
typedef __attribute__((ext_vector_type(8))) unsigned short us8;
typedef unsigned int u32;

#define NTOK  16384
#define EMBED 512
#define FFN   2048
#define NQ    10
#define BM    128
#define BN    64
#define NKT   32          // K-tiles of 64 k

__device__ __forceinline__ unsigned short f2bf(float f) {
  union { float f; unsigned int u; } a; a.f = f;
  unsigned int r = a.u + 0x7FFFu + ((a.u >> 16) & 1u);   // RNE
  return (unsigned short)(r >> 16);
}

__device__ __forceinline__ void gload_lds16(const void* g, void* l) {
  __builtin_amdgcn_global_load_lds(
      (const __attribute__((address_space(1))) unsigned int*)g,
      (__attribute__((address_space(3))) unsigned int*)l, 16, 0, 0);
}

// ---------------- K0: fused prep (W2f + Qf + W1f), one launch ----------------
// W2f[((tile*128+kb)*64+l)*8+e] = W2[col=tile*32+(l&31)][k=kb*16+(l>>5)*8+e]
// Qf [(tile*64+l)*8+e]          = qaug[wire=(l>>5)*8+e][token=tile*32+(l&31)]
// W1f[(blk*64+l)*8+e]           = W1aug[wire=(l>>5)*8+e][k=blk*32+(l&31)]
__global__ __launch_bounds__(256) void k_prep(const float* __restrict__ x,
                                              const float* __restrict__ theta,
                                              const float* __restrict__ W1,
                                              const float* __restrict__ b1,
                                              const float* __restrict__ W2,
                                              unsigned short* __restrict__ W2f,
                                              unsigned short* __restrict__ W1f,
                                              unsigned short* __restrict__ Qf) {
  int bb = blockIdx.x;
  if (bb < 512) {                       // ---- W2f: 131072 chunks ----
    int gid = bb * 256 + threadIdx.x;
    int l = gid & 63, kb = (gid >> 6) & 127, tile = gid >> 13;
    int col = tile * 32 + (l & 31);
    int k0 = kb * 16 + (l >> 5) * 8;
    const float* src = W2 + (size_t)col * FFN + k0;
    float4 v0 = *(const float4*)src;
    float4 v1 = *(const float4*)(src + 4);
    us8 o;
    o[0] = f2bf(v0.x); o[1] = f2bf(v0.y); o[2] = f2bf(v0.z); o[3] = f2bf(v0.w);
    o[4] = f2bf(v1.x); o[5] = f2bf(v1.y); o[6] = f2bf(v1.z); o[7] = f2bf(v1.w);
    *(us8*)(W2f + (size_t)gid * 8) = o;
  } else if (bb < 640) {                // ---- Qf: 32768 chunks ----
    int gid = (bb - 512) * 256 + threadIdx.x;
    int l = gid & 63, tile = gid >> 6;
    int tok = tile * 32 + (l & 31), g = l >> 5;
    const int masks[NQ] = {0x2AB,0x3FD,0x3FA,0x3F5,0x3EA,0x3D5,0x3AA,0x355,0x2AA,0x155};
    float z[NQ], qv[NQ];
#pragma unroll
    for (int w = 0; w < NQ; ++w)
      z[w] = __builtin_cosf(x[(size_t)tok * EMBED + w]) * __builtin_cosf(theta[w]);
#pragma unroll
    for (int w = 0; w < NQ; ++w) {
      float p = 1.f;
#pragma unroll
      for (int v = 0; v < NQ; ++v)
        if ((masks[w] >> v) & 1) p *= z[v];
      qv[w] = p;
    }
    us8 o = (us8)0;
    if (g == 0) {
#pragma unroll
      for (int e = 0; e < 8; ++e) o[e] = f2bf(qv[e]);
    } else {
      o[0] = f2bf(qv[8]); o[1] = f2bf(qv[9]); o[2] = f2bf(1.f);
    }
    *(us8*)(Qf + (size_t)gid * 8) = o;
  } else {                              // ---- W1f: 4096 chunks ----
    int gid = (bb - 640) * 256 + threadIdx.x;
    int l = gid & 63, blk = gid >> 6;
    int k = blk * 32 + (l & 31);
    int wg = (l >> 5) * 8;
    us8 o;
#pragma unroll
    for (int e = 0; e < 8; ++e) {
      int wire = wg + e;
      float v = (wire < NQ) ? W1[k * NQ + wire] : (wire == NQ ? b1[k] : 0.f);
      o[e] = f2bf(v);
    }
    *(us8*)(W1f + (size_t)gid * 8) = o;
  }
}

// ---------------- K1: fused H-gen + GEMM, pipelined, 4 blocks/CU ----------------
__global__ __launch_bounds__(256, 4) void k_fused(const unsigned short* __restrict__ Qf,
                                                  const unsigned short* __restrict__ W1f,
                                                  const unsigned short* __restrict__ W2f,
                                                  const float* __restrict__ b2,
                                                  float* __restrict__ out) {
  __shared__ short Bw[2][8 * 64 * 8];    // 2 x 8KB: [tile2*4+kb][lane][8], frag order
  __shared__ short W1s[2][2 * 64 * 8];   // 2 x 2KB: slot[j&1] holds W1 slice j

  // XCD-aware bijective swizzle: 1024 blocks, 128 consecutive per XCD; n fastest.
  int bid = blockIdx.x;
  int swz = (bid & 7) * 128 + (bid >> 3);
  const int m0 = (swz >> 3) * BM;      // 128 m-tiles
  const int n0 = (swz & 7) * BN;       // 8 n-tiles
  const int tid  = threadIdx.x;
  const int lane = tid & 63;
  const int wave = tid >> 6;           // 4 waves, each 32 tok x 64 cols
  const int h = lane >> 5, t31 = lane & 31;
  const int nt0 = n0 >> 5;             // global col-tile base (2 tiles of 32)

  // q_aug B-frag for this wave's 32 tokens (single load, register-resident)
  bf16x8 qf = *(const bf16x8*)&Qf[(((size_t)(m0 >> 5) + wave) * 64 + lane) * 8];

  f32x16 acc[2] = {};
  bf16x8 aqA0, aqA1, aqA2, aqA3;       // A-quads for even kt
  bf16x8 aqB0, aqB1, aqB2, aqB3;       // A-quads for odd kt

#define STAGE_BW(KT, B)                                                         \
  { _Pragma("unroll")                                                           \
    for (int hf = 0; hf < 2; ++hf) {                                            \
      int ch = hf * 256 + tid;                                                  \
      int tile2 = ch >> 8, kb = (ch >> 6) & 3, ln = ch & 63;                    \
      gload_lds16(&W2f[(((size_t)(nt0 + tile2) * 128 + (KT) * 4 + kb) * 64 + ln) * 8], \
                  &Bw[B][ch * 8]);                                              \
    } }

#define STAGE_W1(KT, S)                                                         \
  { if (tid < 128)                                                              \
      gload_lds16(&W1f[(((size_t)(KT) * 2 + (tid >> 6)) * 64 + (tid & 63)) * 8],\
                  &W1s[S][tid * 8]); }

  // relu + RNE cvt_pk (HW, verified R9-R14) + permlane32_swap -> two A-quads
#define POST(D, AQ0, AQ1)                                                       \
  { f32x16 zz = {};                                                             \
    D = __builtin_elementwise_max(D, zz);                                       \
    u32 w0, w1, w2, w3, w4, w5, w6, w7;                                         \
    asm("v_cvt_pk_bf16_f32 %0, %1, %2":"=v"(w0):"v"(D[0]),"v"(D[1]));           \
    asm("v_cvt_pk_bf16_f32 %0, %1, %2":"=v"(w1):"v"(D[2]),"v"(D[3]));           \
    asm("v_cvt_pk_bf16_f32 %0, %1, %2":"=v"(w2):"v"(D[4]),"v"(D[5]));           \
    asm("v_cvt_pk_bf16_f32 %0, %1, %2":"=v"(w3):"v"(D[6]),"v"(D[7]));           \
    asm("v_cvt_pk_bf16_f32 %0, %1, %2":"=v"(w4):"v"(D[8]),"v"(D[9]));           \
    asm("v_cvt_pk_bf16_f32 %0, %1, %2":"=v"(w5):"v"(D[10]),"v"(D[11]));         \
    asm("v_cvt_pk_bf16_f32 %0, %1, %2":"=v"(w6):"v"(D[12]),"v"(D[13]));         \
    asm("v_cvt_pk_bf16_f32 %0, %1, %2":"=v"(w7):"v"(D[14]),"v"(D[15]));         \
    asm("v_permlane32_swap_b32 %0, %1" : "+v"(w0), "+v"(w2));                   \
    asm("v_permlane32_swap_b32 %0, %1" : "+v"(w1), "+v"(w3));                   \
    asm("v_permlane32_swap_b32 %0, %1" : "+v"(w4), "+v"(w6));                   \
    asm("v_permlane32_swap_b32 %0, %1" : "+v"(w5), "+v"(w7));                   \
    union { u32 u[4]; bf16x8 v; } u0, u1;                                       \
    u0.u[0]=w0; u0.u[1]=w1; u0.u[2]=w2; u0.u[3]=w3;                             \
    u1.u[0]=w4; u1.u[1]=w5; u1.u[2]=w6; u1.u[3]=w7;                             \
    AQ0 = u0.v; AQ1 = u1.v; }

  // GEMM(kt) from buffer B with A-quads U0..U3 (j-chains interleaved)
#define GEMM(B, U0, U1, U2, U3)                                                 \
  { bf16x8 bg00 = *(const bf16x8*)&Bw[B][((0 * 4 + 0) * 64 + lane) * 8];        \
    bf16x8 bg01 = *(const bf16x8*)&Bw[B][((0 * 4 + 1) * 64 + lane) * 8];        \
    bf16x8 bg02 = *(const bf16x8*)&Bw[B][((0 * 4 + 2) * 64 + lane) * 8];        \
    bf16x8 bg03 = *(const bf16x8*)&Bw[B][((0 * 4 + 3) * 64 + lane) * 8];        \
    bf16x8 bg10 = *(const bf16x8*)&Bw[B][((1 * 4 + 0) * 64 + lane) * 8];        \
    bf16x8 bg11 = *(const bf16x8*)&Bw[B][((1 * 4 + 1) * 64 + lane) * 8];        \
    bf16x8 bg12 = *(const bf16x8*)&Bw[B][((1 * 4 + 2) * 64 + lane) * 8];        \
    bf16x8 bg13 = *(const bf16x8*)&Bw[B][((1 * 4 + 3) * 64 + lane) * 8];        \
    acc[0] = __builtin_amdgcn_mfma_f32_32x32x16_bf16(U0, bg00, acc[0], 0, 0, 0); \
    acc[1] = __builtin_amdgcn_mfma_f32_32x32x16_bf16(U0, bg10, acc[1], 0, 0, 0); \
    acc[0] = __builtin_amdgcn_mfma_f32_32x32x16_bf16(U1, bg01, acc[0], 0, 0, 0); \
    acc[1] = __builtin_amdgcn_mfma_f32_32x32x16_bf16(U1, bg11, acc[1], 0, 0, 0); \
    acc[0] = __builtin_amdgcn_mfma_f32_32x32x16_bf16(U2, bg02, acc[0], 0, 0, 0); \
    acc[1] = __builtin_amdgcn_mfma_f32_32x32x16_bf16(U2, bg12, acc[1], 0, 0, 0); \
    acc[0] = __builtin_amdgcn_mfma_f32_32x32x16_bf16(U3, bg03, acc[0], 0, 0, 0); \
    acc[1] = __builtin_amdgcn_mfma_f32_32x32x16_bf16(U3, bg13, acc[1], 0, 0, 0); }

  // One kt: wait+barrier; stage kt+1 (Bw) and kt+2 (W1); HGEN(kt+1) -> V-bank
  // (independent of GEMM(kt) on U-bank -> scheduler interleaves all 10 mfma).
#define BODY(KT, BUF, WSL, U0, U1, U2, U3, V0, V1, V2, V3)                      \
  { asm volatile("s_waitcnt vmcnt(0)" ::: "memory");                            \
    __builtin_amdgcn_s_barrier();                                               \
    asm volatile("" ::: "memory");                                              \
    const bool hasN  = (KT) + 1 < NKT;                                          \
    const bool hasN2 = (KT) + 2 < NKT;                                          \
    if (hasN)  STAGE_BW((KT) + 1, (BUF) ^ 1);                                   \
    if (hasN2) STAGE_W1((KT) + 2, (WSL) ^ 1);                                   \
    if (hasN) {                                                                 \
      bf16x8 wf0 = *(const bf16x8*)&W1s[WSL][(0 * 64 + lane) * 8];              \
      bf16x8 wf1 = *(const bf16x8*)&W1s[WSL][(1 * 64 + lane) * 8];              \
      f32x16 zz = {};                                                           \
      f32x16 d0 = __builtin_amdgcn_mfma_f32_32x32x16_bf16(wf0, qf, zz, 0, 0, 0); \
      f32x16 d1 = __builtin_amdgcn_mfma_f32_32x32x16_bf16(wf1, qf, zz, 0, 0, 0); \
      POST(d0, V0, V1);                                                         \
      POST(d1, V2, V3);                                                         \
      GEMM(BUF, U0, U1, U2, U3);                                                \
    } else {                                                                    \
      GEMM(BUF, U0, U1, U2, U3);                                                \
    } }

  // ---- prologue: stage W1(0)->slot0, W1(1)->slot1, Bw(0)->buf0; HGEN(0)->aqA ----
  STAGE_W1(0, 0);
  STAGE_W1(1, 1);
  STAGE_BW(0, 0);
  asm volatile("s_waitcnt vmcnt(0)" ::: "memory");
  __builtin_amdgcn_s_barrier();
  {
    bf16x8 wf0 = *(const bf16x8*)&W1s[0][(0 * 64 + lane) * 8];
    bf16x8 wf1 = *(const bf16x8*)&W1s[0][(1 * 64 + lane) * 8];
    f32x16 zz = {};
    f32x16 d0 = __builtin_amdgcn_mfma_f32_32x32x16_bf16(wf0, qf, zz, 0, 0, 0);
    f32x16 d1 = __builtin_amdgcn_mfma_f32_32x32x16_bf16(wf1, qf, zz, 0, 0, 0);
    POST(d0, aqA0, aqA1);
    POST(d1, aqA2, aqA3);
  }
  // loop's kt=0 barrier protects W1s slot0 before stage W1(2)->slot0.

  // ---- main loop: 2 kt per iteration (static banks/buffers) ----
  for (int p2 = 0; p2 < NKT / 2; ++p2) {
    const int kt = 2 * p2;
    BODY(kt,     0, 1, aqA0, aqA1, aqA2, aqA3, aqB0, aqB1, aqB2, aqB3);
    BODY(kt + 1, 1, 0, aqB0, aqB1, aqB2, aqB3, aqA0, aqA1, aqA2, aqA3);
  }

  // ---- epilogue: out = acc + b2 ----
#pragma unroll
  for (int j = 0; j < 2; ++j) {
    const int col = n0 + j * 32 + t31;
    const float bbv = b2[col];
#pragma unroll
    for (int r = 0; r < 16; ++r) {
      int tok = m0 + wave * 32 + (r & 3) + 8 * (r >> 2) + 4 * h;
      out[(size_t)tok * EMBED + col] = acc[j][r] + bbv;
    }
  }
#undef STAGE_BW
#undef STAGE_W1
#undef POST
#undef GEMM
#undef BODY
}

extern "C" void kernel_launch(void* const* d_in, const int* in_sizes, int n_in,
                              void* d_out, int out_size, void* d_ws, size_t ws_size,
                              hipStream_t stream) {
  const float* x     = (const float*)d_in[0];
  const float* theta = (const float*)d_in[1];
  const float* W1    = (const float*)d_in[2];
  const float* b1    = (const float*)d_in[3];
  const float* W2    = (const float*)d_in[4];
  const float* b2    = (const float*)d_in[5];
  float* out = (float*)d_out;

  char* ws = (char*)d_ws;
  unsigned short* W2f = (unsigned short*)ws;                          // 2 MB
  unsigned short* W1f = (unsigned short*)(ws + (2u << 20));           // 64 KB
  unsigned short* Qfg = (unsigned short*)(ws + (2u << 20) + (64u << 10)); // 512 KB

  k_prep <<<656, 256, 0, stream>>>(x, theta, W1, b1, W2, W2f, W1f, Qfg);
  k_fused<<<(NTOK / BM) * (EMBED / BN), 256, 0, stream>>>(Qfg, W1f, W2f, b2, out);
}